// Round 1
// baseline (272.400 us; speedup 1.0000x reference)
//
#include <hip/hip_runtime.h>

// VectorQuantizer: z_e (32,64,64,64) fp32 -> M=131072 rows of D=64; K=512 codes.
// Out layout (all fp32): [0]=loss | [1 .. 1+NELEM)=quantized_st | [1+NELEM ..)=indices as float
constexpr int D4     = 16;        // 64 floats = 16 float4
constexpr int KCODES = 512;
constexpr int NROWS  = 131072;
constexpr int NELEM  = 8388608;   // 32*64*64*64

// ws layout (floats): [0..512) = en2 (||e_k||^2), [512..1024) = per-block loss partials

__global__ void __launch_bounds__(512) vq_prep(const float* __restrict__ emb,
                                               float* __restrict__ en2) {
    int k = threadIdx.x;  // 512 threads, one code each
    const float4* e4 = (const float4*)(emb + (size_t)k * 64);
    float a = 0.f, b = 0.f, c = 0.f, d = 0.f;
#pragma unroll
    for (int i = 0; i < D4; ++i) {
        float4 v = e4[i];
        a += v.x * v.x; b += v.y * v.y; c += v.z * v.z; d += v.w * v.w;
    }
    en2[k] = (a + b) + (c + d);
}

__global__ void __launch_bounds__(256) vq_main(const float* __restrict__ z,
                                               const float* __restrict__ emb,
                                               const float* __restrict__ en2,
                                               float* __restrict__ out,
                                               float* __restrict__ partials) {
    const int m = blockIdx.x * 256 + threadIdx.x;  // one row per thread

    // Load z row into registers (aligned float4: base + m*256B)
    const float4* zp = (const float4*)(z + (size_t)m * 64);
    float4 za[D4];
#pragma unroll
    for (int i = 0; i < D4; ++i) za[i] = zp[i];

    // zn2 = sum(z^2) — common additive term; replicated so distance quantization
    // at ulp(64) matches the reference's fp32 arithmetic.
    float zn2;
    {
        float a = 0.f, b = 0.f, c = 0.f, d = 0.f;
#pragma unroll
        for (int i = 0; i < D4; ++i) {
            a += za[i].x * za[i].x; b += za[i].y * za[i].y;
            c += za[i].z * za[i].z; d += za[i].w * za[i].w;
        }
        zn2 = (a + b) + (c + d);
    }

    float best = 3.402823466e38f;
    int bidx = 0;
    // k is wave-uniform -> emb/en2 loads should scalarize (s_load), FMA-bound loop.
    for (int k = 0; k < KCODES; ++k) {
        const float4* ep = (const float4*)(emb + (size_t)k * 64);
        float a = 0.f, b = 0.f, c = 0.f, d = 0.f;
#pragma unroll
        for (int i = 0; i < D4; ++i) {
            float4 e = ep[i];
            a += za[i].x * e.x; b += za[i].y * e.y;
            c += za[i].z * e.z; d += za[i].w * e.w;
        }
        float dot  = (a + b) + (c + d);
        float dist = (zn2 + en2[k]) - 2.0f * dot;  // replicate (||z||^2 + ||e||^2) - 2*z.e
        if (dist < best) { best = dist; bidx = k; }  // strict < keeps first index (np.argmin)
    }

    // Gather winning code, write quantized_st = z + (e - z) (replicated STE arithmetic),
    // accumulate this row's squared-diff for the loss.
    const float* eb = emb + (size_t)bidx * 64;
    float* qo = out + 1 + (size_t)m * 64;  // +1 float offset: scalar stores (16B-misaligned)
    float lsum = 0.f;
#pragma unroll
    for (int i = 0; i < D4; ++i) {
        float zv, ev, qv, df;
        zv = za[i].x; ev = eb[4*i+0]; qv = zv + (ev - zv); df = qv - zv; lsum += df*df; qo[4*i+0] = qv;
        zv = za[i].y; ev = eb[4*i+1]; qv = zv + (ev - zv); df = qv - zv; lsum += df*df; qo[4*i+1] = qv;
        zv = za[i].z; ev = eb[4*i+2]; qv = zv + (ev - zv); df = qv - zv; lsum += df*df; qo[4*i+2] = qv;
        zv = za[i].w; ev = eb[4*i+3]; qv = zv + (ev - zv); df = qv - zv; lsum += df*df; qo[4*i+3] = qv;
    }
    out[1 + NELEM + m] = (float)bidx;  // index as float (out buffer is fp32)

    // Block reduction of loss partial: wave shuffle then 4-wave combine via LDS.
#pragma unroll
    for (int off = 32; off; off >>= 1) lsum += __shfl_down(lsum, off, 64);
    __shared__ float wred[4];
    if ((threadIdx.x & 63) == 0) wred[threadIdx.x >> 6] = lsum;
    __syncthreads();
    if (threadIdx.x == 0)
        partials[blockIdx.x] = (wred[0] + wred[1]) + (wred[2] + wred[3]);
}

__global__ void __launch_bounds__(64) vq_loss(const float* __restrict__ partials,
                                              float* __restrict__ out) {
    int t = threadIdx.x;  // single wave
    double s = 0.0;
    for (int i = t; i < 512; i += 64) s += (double)partials[i];
#pragma unroll
    for (int off = 32; off; off >>= 1) s += __shfl_down(s, off, 64);
    if (t == 0) out[0] = (float)(1.25 * s / 8388608.0);  // recon + 0.25*commit
}

extern "C" void kernel_launch(void* const* d_in, const int* in_sizes, int n_in,
                              void* d_out, int out_size, void* d_ws, size_t ws_size,
                              hipStream_t stream) {
    const float* z   = (const float*)d_in[0];
    const float* emb = (const float*)d_in[1];
    float* out = (float*)d_out;
    float* ws  = (float*)d_ws;
    float* en2      = ws;        // 512 floats
    float* partials = ws + 512;  // 512 floats

    vq_prep<<<1, 512, 0, stream>>>(emb, en2);
    vq_main<<<NROWS / 256, 256, 0, stream>>>(z, emb, en2, out, partials);
    vq_loss<<<1, 64, 0, stream>>>(partials, out);
}

// Round 2
// 211.764 us; speedup vs baseline: 1.2863x; 1.2863x over previous
//
#include <hip/hip_runtime.h>

// VectorQuantizer: z_e (32,64,64,64) fp32 -> M=131072 rows of D=64; K=512 codes.
// Out layout (fp32): [0]=loss | [1 .. 1+NELEM)=quantized_st | [1+NELEM ..)=indices as float
// Numerics are a bit-exact replication of the np reference:
//   dist = (||z||^2 + ||e||^2) - 2*dot, fp32, 4-accumulator dot, strict-< argmin.
constexpr int KCODES = 512;
constexpr int NROWS  = 131072;
constexpr int NELEM  = 8388608;   // 32*64*64*64
constexpr int NBLK   = 2048;      // 64 rows per block

// Block = 256 threads = 4 waves. Wave w handles codes [128w, 128w+128) for the
// block's 64 rows (lane = row). K is wave-uniform -> emb loads scalarize.
// launch_bounds(256,4): VGPR cap 128 — za(64 VGPRs) stays in registers (round-1
// default capped at 44 VGPRs and spilled the z-row to scratch: +50MB WRITE_SIZE).
__global__ __launch_bounds__(256, 4) void vq_main(const float* __restrict__ z,
                                                  const float* __restrict__ emb,
                                                  float* __restrict__ out,
                                                  float* __restrict__ partials) {
    __shared__ float s_en2[KCODES];
    __shared__ float s_best[4][64];
    __shared__ int   s_bidx[4][64];
    __shared__ float s_wred[4];

    const int tid  = threadIdx.x;
    const int lane = tid & 63;
    const int wid  = __builtin_amdgcn_readfirstlane(tid >> 6);  // force wave-uniform

    // ---- en2 into LDS: 2 codes/thread, identical arithmetic to round-1 prep ----
#pragma unroll
    for (int c = 0; c < 2; ++c) {
        const int k = tid * 2 + c;
        const float4* e4 = (const float4*)(emb + (size_t)k * 64);
        float a = 0.f, b = 0.f, cc = 0.f, d = 0.f;
#pragma unroll
        for (int i = 0; i < 16; ++i) {
            float4 v = e4[i];
            a += v.x * v.x; b += v.y * v.y; cc += v.z * v.z; d += v.w * v.w;
        }
        s_en2[k] = (a + b) + (cc + d);
    }

    // ---- z row into registers ----
    const int m = blockIdx.x * 64 + lane;
    const float4* zp = (const float4*)(z + (size_t)m * 64);
    float4 za[16];
#pragma unroll
    for (int i = 0; i < 16; ++i) za[i] = zp[i];

    float zn2;
    {
        float a = 0.f, b = 0.f, c = 0.f, d = 0.f;
#pragma unroll
        for (int i = 0; i < 16; ++i) {
            a += za[i].x * za[i].x; b += za[i].y * za[i].y;
            c += za[i].z * za[i].z; d += za[i].w * za[i].w;
        }
        zn2 = (a + b) + (c + d);
    }

    __syncthreads();  // s_en2 ready

    // ---- argmin over this wave's 128 codes ----
    float best = 3.402823466e38f;
    int bidx = 0;
    const int kbase = wid * 128;
    for (int k = kbase; k < kbase + 128; ++k) {
        const float4* ep = (const float4*)(emb + (size_t)k * 64);  // wave-uniform -> s_load
        float a = 0.f, b = 0.f, c = 0.f, d = 0.f;
#pragma unroll
        for (int i = 0; i < 16; ++i) {
            float4 e = ep[i];
            a += za[i].x * e.x; b += za[i].y * e.y;
            c += za[i].z * e.z; d += za[i].w * e.w;
        }
        float dot  = (a + b) + (c + d);
        float dist = (zn2 + s_en2[k]) - 2.0f * dot;
        if (dist < best) { best = dist; bidx = k; }  // strict <: first-index tie-break
    }
    s_best[wid][lane] = best;
    s_bidx[wid][lane] = bidx;
    __syncthreads();

    // ---- merge 4 waves' candidates (ascending w + strict < keeps lowest k) ----
    // Epilogue: thread t -> row r = t>>2, quarter q = t&3 (16 floats each).
    const int r = tid >> 2, q = tid & 3;
    float fb = s_best[0][r];
    int   fi = s_bidx[0][r];
#pragma unroll
    for (int w = 1; w < 4; ++w) {
        float cb = s_best[w][r];
        int   ci = s_bidx[w][r];
        if (cb < fb) { fb = cb; fi = ci; }
    }
    const int mr = blockIdx.x * 64 + r;
    const float4* zr = (const float4*)(z   + (size_t)mr * 64 + q * 16);
    const float4* er = (const float4*)(emb + (size_t)fi * 64 + q * 16);
    float* qo = out + 1 + (size_t)mr * 64 + q * 16;  // out+1: 4B-aligned only -> scalar stores
    float lsum = 0.f;
#pragma unroll
    for (int j = 0; j < 4; ++j) {
        float4 zv = zr[j];
        float4 ev = er[j];
        float q0 = zv.x + (ev.x - zv.x); float d0 = q0 - zv.x; lsum += d0 * d0;
        float q1 = zv.y + (ev.y - zv.y); float d1 = q1 - zv.y; lsum += d1 * d1;
        float q2 = zv.z + (ev.z - zv.z); float d2 = q2 - zv.z; lsum += d2 * d2;
        float q3 = zv.w + (ev.w - zv.w); float d3 = q3 - zv.w; lsum += d3 * d3;
        qo[4*j+0] = q0; qo[4*j+1] = q1; qo[4*j+2] = q2; qo[4*j+3] = q3;
    }
    if (q == 0) out[1 + NELEM + mr] = (float)fi;

    // ---- loss partial: wave shuffle reduce, then 4-wave combine ----
#pragma unroll
    for (int off = 32; off; off >>= 1) lsum += __shfl_down(lsum, off, 64);
    if (lane == 0) s_wred[wid] = lsum;
    __syncthreads();
    if (tid == 0)
        partials[blockIdx.x] = (s_wred[0] + s_wred[1]) + (s_wred[2] + s_wred[3]);
}

__global__ void __launch_bounds__(64) vq_loss(const float* __restrict__ partials,
                                              float* __restrict__ out) {
    int t = threadIdx.x;  // single wave
    double s = 0.0;
    for (int i = t; i < NBLK; i += 64) s += (double)partials[i];
#pragma unroll
    for (int off = 32; off; off >>= 1) s += __shfl_down(s, off, 64);
    if (t == 0) out[0] = (float)(1.25 * s / 8388608.0);  // recon + 0.25*commit
}

extern "C" void kernel_launch(void* const* d_in, const int* in_sizes, int n_in,
                              void* d_out, int out_size, void* d_ws, size_t ws_size,
                              hipStream_t stream) {
    const float* z   = (const float*)d_in[0];
    const float* emb = (const float*)d_in[1];
    float* out = (float*)d_out;
    float* partials = (float*)d_ws;  // NBLK floats

    vq_main<<<NBLK, 256, 0, stream>>>(z, emb, out, partials);
    vq_loss<<<1, 64, 0, stream>>>(partials, out);
}

// Round 3
// 203.031 us; speedup vs baseline: 1.3417x; 1.0430x over previous
//
#include <hip/hip_runtime.h>

// VectorQuantizer: z_e (32,64,64,64) fp32 -> M=131072 rows of D=64; K=512 codes.
// Out layout (fp32): [0]=loss | [1 .. 1+NELEM)=quantized_st | [1+NELEM ..)=indices as float
// Numerics bit-exactly replicate the np reference (passed absmax 0.0 in R1/R2):
//   dist = (||z||^2 + ||e||^2) - 2*dot, fp32 quad-accumulator dot, strict-< argmin.
constexpr int KCODES = 512;
constexpr int NELEM  = 8388608;   // 32*64*64*64
constexpr int NBLK   = 2048;      // 64 rows per block

typedef float v4f __attribute__((ext_vector_type(4)));

// Block = 256 threads = 4 waves. Wave w handles codes [128w, 128w+128) for the
// block's 64 rows (lane = row); K wave-uniform -> emb loads scalarize (s_load).
// waves_per_eu(4,4): pin occupancy target at 4 waves/SIMD (128-reg budget) so the
// backend keeps the 64-float z-row register-resident instead of re-loading from L1
// each k-iter (R2: VGPR_Count=44 + VALUBusy 54% = z-row sunk to in-loop loads).
__global__ __launch_bounds__(256) __attribute__((amdgpu_waves_per_eu(4, 4)))
void vq_main(const float* __restrict__ z,
             const float* __restrict__ emb,
             float* __restrict__ out,
             float* __restrict__ partials) {
    __shared__ float s_en2[KCODES];
    __shared__ float s_best[4][64];
    __shared__ int   s_bidx[4][64];
    __shared__ float s_wred[4];

    const int tid  = threadIdx.x;
    const int lane = tid & 63;
    const int wid  = __builtin_amdgcn_readfirstlane(tid >> 6);  // wave-uniform

    // ---- en2 into LDS: 2 codes/thread, same arithmetic as R1/R2 ----
#pragma unroll
    for (int c = 0; c < 2; ++c) {
        const int k = tid * 2 + c;
        const v4f* e4 = (const v4f*)(emb + (size_t)k * 64);
        float a = 0.f, b = 0.f, cc = 0.f, d = 0.f;
#pragma unroll
        for (int i = 0; i < 16; ++i) {
            v4f v = e4[i];
            a += v.x * v.x; b += v.y * v.y; cc += v.z * v.z; d += v.w * v.w;
        }
        s_en2[k] = (a + b) + (cc + d);
    }

    // ---- z row into named registers ----
    const int m = blockIdx.x * 64 + lane;
    const v4f* zp = (const v4f*)(z + (size_t)m * 64);
    v4f z0 = zp[0],  z1 = zp[1],  z2 = zp[2],  z3 = zp[3],
        z4 = zp[4],  z5 = zp[5],  z6 = zp[6],  z7 = zp[7],
        z8 = zp[8],  z9 = zp[9],  z10 = zp[10], z11 = zp[11],
        z12 = zp[12], z13 = zp[13], z14 = zp[14], z15 = zp[15];

    float zn2;
    {
        float a = 0.f, b = 0.f, c = 0.f, d = 0.f;
#define SQ4(i) { a += z##i.x * z##i.x; b += z##i.y * z##i.y; c += z##i.z * z##i.z; d += z##i.w * z##i.w; }
        SQ4(0) SQ4(1) SQ4(2) SQ4(3) SQ4(4) SQ4(5) SQ4(6) SQ4(7)
        SQ4(8) SQ4(9) SQ4(10) SQ4(11) SQ4(12) SQ4(13) SQ4(14) SQ4(15)
#undef SQ4
        zn2 = (a + b) + (c + d);
    }

    // Pin the z-row into VGPRs: asm outputs are opaque, so later uses cannot be
    // replaced by re-loads from global memory (the R2 failure mode).
    asm volatile("" : "+v"(z0), "+v"(z1), "+v"(z2), "+v"(z3),
                      "+v"(z4), "+v"(z5), "+v"(z6), "+v"(z7),
                      "+v"(z8), "+v"(z9), "+v"(z10), "+v"(z11),
                      "+v"(z12), "+v"(z13), "+v"(z14), "+v"(z15));

    __syncthreads();  // s_en2 ready

    // ---- argmin over this wave's 128 codes ----
    float best = 3.402823466e38f;
    int bidx = 0;
    const int kbase = wid * 128;
    for (int k = kbase; k < kbase + 128; ++k) {
        const v4f* ep = (const v4f*)(emb + (size_t)k * 64);  // uniform -> s_load
        float a = 0.f, b = 0.f, c = 0.f, d = 0.f;
#define FMA4(i) { v4f e = ep[i]; a += z##i.x * e.x; b += z##i.y * e.y; c += z##i.z * e.z; d += z##i.w * e.w; }
        FMA4(0) FMA4(1) FMA4(2) FMA4(3) FMA4(4) FMA4(5) FMA4(6) FMA4(7)
        FMA4(8) FMA4(9) FMA4(10) FMA4(11) FMA4(12) FMA4(13) FMA4(14) FMA4(15)
#undef FMA4
        float dot  = (a + b) + (c + d);
        float dist = (zn2 + s_en2[k]) - 2.0f * dot;
        if (dist < best) { best = dist; bidx = k; }  // strict <: first-index tie-break
    }
    s_best[wid][lane] = best;
    s_bidx[wid][lane] = bidx;
    __syncthreads();

    // ---- merge 4 waves (ascending w + strict < keeps lowest index) ----
    // Epilogue: thread t -> row r = t>>2, quarter q = t&3 (16 floats each).
    const int r = tid >> 2, q = tid & 3;
    float fb = s_best[0][r];
    int   fi = s_bidx[0][r];
#pragma unroll
    for (int w = 1; w < 4; ++w) {
        float cb = s_best[w][r];
        int   ci = s_bidx[w][r];
        if (cb < fb) { fb = cb; fi = ci; }
    }
    const int mr = blockIdx.x * 64 + r;
    const float4* zr = (const float4*)(z   + (size_t)mr * 64 + q * 16);
    const float4* er = (const float4*)(emb + (size_t)fi * 64 + q * 16);
    float* qo = out + 1 + (size_t)mr * 64 + q * 16;  // out+1: 4B-aligned -> scalar stores
    float lsum = 0.f;
#pragma unroll
    for (int j = 0; j < 4; ++j) {
        float4 zv = zr[j];
        float4 ev = er[j];
        float q0 = zv.x + (ev.x - zv.x); float d0 = q0 - zv.x; lsum += d0 * d0;
        float q1 = zv.y + (ev.y - zv.y); float d1 = q1 - zv.y; lsum += d1 * d1;
        float q2 = zv.z + (ev.z - zv.z); float d2 = q2 - zv.z; lsum += d2 * d2;
        float q3 = zv.w + (ev.w - zv.w); float d3 = q3 - zv.w; lsum += d3 * d3;
        qo[4*j+0] = q0; qo[4*j+1] = q1; qo[4*j+2] = q2; qo[4*j+3] = q3;
    }
    if (q == 0) out[1 + NELEM + mr] = (float)fi;

    // ---- loss partial: wave shuffle reduce, then 4-wave combine ----
#pragma unroll
    for (int off = 32; off; off >>= 1) lsum += __shfl_down(lsum, off, 64);
    if (lane == 0) s_wred[wid] = lsum;
    __syncthreads();
    if (tid == 0)
        partials[blockIdx.x] = (s_wred[0] + s_wred[1]) + (s_wred[2] + s_wred[3]);
}

__global__ void __launch_bounds__(256) vq_loss(const float* __restrict__ partials,
                                               float* __restrict__ out) {
    const int t = threadIdx.x;
    const float4* p4 = (const float4*)partials;  // 2048 floats = 512 float4
    double s = 0.0;
#pragma unroll
    for (int i = 0; i < 2; ++i) {
        float4 v = p4[t + i * 256];
        s += (double)v.x + (double)v.y + (double)v.z + (double)v.w;
    }
#pragma unroll
    for (int off = 32; off; off >>= 1) s += __shfl_down(s, off, 64);
    __shared__ double sw[4];
    if ((t & 63) == 0) sw[t >> 6] = s;
    __syncthreads();
    if (t == 0) out[0] = (float)(1.25 * ((sw[0] + sw[1]) + (sw[2] + sw[3])) / 8388608.0);
}

extern "C" void kernel_launch(void* const* d_in, const int* in_sizes, int n_in,
                              void* d_out, int out_size, void* d_ws, size_t ws_size,
                              hipStream_t stream) {
    const float* z   = (const float*)d_in[0];
    const float* emb = (const float*)d_in[1];
    float* out = (float*)d_out;
    float* partials = (float*)d_ws;  // NBLK floats

    vq_main<<<NBLK, 256, 0, stream>>>(z, emb, out, partials);
    vq_loss<<<1, 256, 0, stream>>>(partials, out);
}

// Round 4
// 195.072 us; speedup vs baseline: 1.3964x; 1.0408x over previous
//
#include <hip/hip_runtime.h>

// VectorQuantizer: z_e (32,64,64,64) fp32 -> M=131072 rows of D=64; K=512 codes.
// Out layout (fp32): [0]=loss | [1 .. 1+NELEM)=quantized_st | [1+NELEM ..)=indices as float
// Numerics bit-exactly replicate the np reference (absmax 0.0 in R1-R3):
//   dist = (||z||^2 + ||e||^2) - 2*dot, fp32 quad-accumulator dot, strict-< argmin.
// R4: 2 rows/lane — each scalar e-row fetch feeds 128 FMAs (was 64), raising
// per-wave duty past the s_load latency (R3: VALUBusy 55%, serial s_load->FMA chain).
constexpr int KCODES = 512;
constexpr int NELEM  = 8388608;   // 32*64*64*64
constexpr int NBLK   = 1024;      // 128 rows per block

typedef float v4f __attribute__((ext_vector_type(4)));

// Block = 256 threads = 4 waves. Wave w handles codes [128w, 128w+128) for the
// block's 128 rows; lane l owns rows (blk*128+l) and (blk*128+64+l).
// waves_per_eu(3,3): 170-reg budget fits 2 z-rows (128 VGPR) + misc without the
// compiler sinking z back to per-iter loads (R2 failure) or spilling.
__global__ __launch_bounds__(256) __attribute__((amdgpu_waves_per_eu(3, 3)))
void vq_main(const float* __restrict__ z,
             const float* __restrict__ emb,
             float* __restrict__ out) {
    __shared__ float s_en2[KCODES];
    __shared__ float s_best[4][128];
    __shared__ int   s_bidx[4][128];
    __shared__ float s_wred[4];

    const int tid  = threadIdx.x;
    const int lane = tid & 63;
    const int wid  = __builtin_amdgcn_readfirstlane(tid >> 6);  // wave-uniform

    // ---- en2 into LDS: 2 codes/thread, arithmetic frozen since R1 ----
#pragma unroll
    for (int c = 0; c < 2; ++c) {
        const int k = tid * 2 + c;
        const v4f* e4 = (const v4f*)(emb + (size_t)k * 64);
        float a = 0.f, b = 0.f, cc = 0.f, d = 0.f;
#pragma unroll
        for (int i = 0; i < 16; ++i) {
            v4f v = e4[i];
            a += v.x * v.x; b += v.y * v.y; cc += v.z * v.z; d += v.w * v.w;
        }
        s_en2[k] = (a + b) + (cc + d);
    }

    // ---- two z rows into named registers ----
    const int mA = blockIdx.x * 128 + lane;
    const int mB = mA + 64;
    const v4f* zpA = (const v4f*)(z + (size_t)mA * 64);
    const v4f* zpB = (const v4f*)(z + (size_t)mB * 64);
    v4f zA0 = zpA[0],  zA1 = zpA[1],  zA2 = zpA[2],  zA3 = zpA[3],
        zA4 = zpA[4],  zA5 = zpA[5],  zA6 = zpA[6],  zA7 = zpA[7],
        zA8 = zpA[8],  zA9 = zpA[9],  zA10 = zpA[10], zA11 = zpA[11],
        zA12 = zpA[12], zA13 = zpA[13], zA14 = zpA[14], zA15 = zpA[15];
    v4f zB0 = zpB[0],  zB1 = zpB[1],  zB2 = zpB[2],  zB3 = zpB[3],
        zB4 = zpB[4],  zB5 = zpB[5],  zB6 = zpB[6],  zB7 = zpB[7],
        zB8 = zpB[8],  zB9 = zpB[9],  zB10 = zpB[10], zB11 = zpB[11],
        zB12 = zpB[12], zB13 = zpB[13], zB14 = zpB[14], zB15 = zpB[15];

    float zn2A, zn2B;
    {
        float a = 0.f, b = 0.f, c = 0.f, d = 0.f;
#define SQ4(i) { a += zA##i.x * zA##i.x; b += zA##i.y * zA##i.y; c += zA##i.z * zA##i.z; d += zA##i.w * zA##i.w; }
        SQ4(0) SQ4(1) SQ4(2) SQ4(3) SQ4(4) SQ4(5) SQ4(6) SQ4(7)
        SQ4(8) SQ4(9) SQ4(10) SQ4(11) SQ4(12) SQ4(13) SQ4(14) SQ4(15)
#undef SQ4
        zn2A = (a + b) + (c + d);
    }
    {
        float a = 0.f, b = 0.f, c = 0.f, d = 0.f;
#define SQ4(i) { a += zB##i.x * zB##i.x; b += zB##i.y * zB##i.y; c += zB##i.z * zB##i.z; d += zB##i.w * zB##i.w; }
        SQ4(0) SQ4(1) SQ4(2) SQ4(3) SQ4(4) SQ4(5) SQ4(6) SQ4(7)
        SQ4(8) SQ4(9) SQ4(10) SQ4(11) SQ4(12) SQ4(13) SQ4(14) SQ4(15)
#undef SQ4
        zn2B = (a + b) + (c + d);
    }

    // Pin both z-rows into VGPRs: asm outputs are opaque -> later uses cannot be
    // replaced with re-loads from global (the R2 failure mode).
    asm volatile("" : "+v"(zA0), "+v"(zA1), "+v"(zA2), "+v"(zA3),
                      "+v"(zA4), "+v"(zA5), "+v"(zA6), "+v"(zA7),
                      "+v"(zA8), "+v"(zA9), "+v"(zA10), "+v"(zA11),
                      "+v"(zA12), "+v"(zA13), "+v"(zA14), "+v"(zA15));
    asm volatile("" : "+v"(zB0), "+v"(zB1), "+v"(zB2), "+v"(zB3),
                      "+v"(zB4), "+v"(zB5), "+v"(zB6), "+v"(zB7),
                      "+v"(zB8), "+v"(zB9), "+v"(zB10), "+v"(zB11),
                      "+v"(zB12), "+v"(zB13), "+v"(zB14), "+v"(zB15));

    __syncthreads();  // s_en2 ready

    // ---- argmin over this wave's 128 codes, both rows per e-fetch ----
    float bestA = 3.402823466e38f, bestB = 3.402823466e38f;
    int bidxA = 0, bidxB = 0;
    const int kbase = wid * 128;
    for (int k = kbase; k < kbase + 128; ++k) {
        const v4f* ep = (const v4f*)(emb + (size_t)k * 64);  // uniform -> s_load
        float aA = 0.f, bA = 0.f, cA = 0.f, dA = 0.f;
        float aB = 0.f, bB = 0.f, cB = 0.f, dB = 0.f;
#define FMA4(i) { v4f e = ep[i]; \
        aA += zA##i.x * e.x; bA += zA##i.y * e.y; cA += zA##i.z * e.z; dA += zA##i.w * e.w; \
        aB += zB##i.x * e.x; bB += zB##i.y * e.y; cB += zB##i.z * e.z; dB += zB##i.w * e.w; }
        FMA4(0) FMA4(1) FMA4(2) FMA4(3) FMA4(4) FMA4(5) FMA4(6) FMA4(7)
        FMA4(8) FMA4(9) FMA4(10) FMA4(11) FMA4(12) FMA4(13) FMA4(14) FMA4(15)
#undef FMA4
        float en2k = s_en2[k];
        float dotA  = (aA + bA) + (cA + dA);
        float dotB  = (aB + bB) + (cB + dB);
        float distA = (zn2A + en2k) - 2.0f * dotA;
        float distB = (zn2B + en2k) - 2.0f * dotB;
        if (distA < bestA) { bestA = distA; bidxA = k; }  // strict <: first-index tie-break
        if (distB < bestB) { bestB = distB; bidxB = k; }
    }
    s_best[wid][lane]      = bestA;
    s_bidx[wid][lane]      = bidxA;
    s_best[wid][lane + 64] = bestB;
    s_bidx[wid][lane + 64] = bidxB;
    __syncthreads();

    // ---- merge 4 waves (ascending w + strict < keeps lowest index) ----
    // Epilogue: thread t -> row r = t>>1 (0..127), half h = t&1 (32 floats each).
    const int r = tid >> 1, h = tid & 1;
    float fb = s_best[0][r];
    int   fi = s_bidx[0][r];
#pragma unroll
    for (int w = 1; w < 4; ++w) {
        float cb = s_best[w][r];
        int   ci = s_bidx[w][r];
        if (cb < fb) { fb = cb; fi = ci; }
    }
    const int mr = blockIdx.x * 128 + r;
    const float4* zr = (const float4*)(z   + (size_t)mr * 64 + h * 32);
    const float4* er = (const float4*)(emb + (size_t)fi * 64 + h * 32);
    float* qo = out + 1 + (size_t)mr * 64 + h * 32;  // out+1: 4B-aligned -> scalar stores
    float lsum = 0.f;
#pragma unroll
    for (int j = 0; j < 8; ++j) {
        float4 zv = zr[j];
        float4 ev = er[j];
        float q0 = zv.x + (ev.x - zv.x); float d0 = q0 - zv.x; lsum += d0 * d0;
        float q1 = zv.y + (ev.y - zv.y); float d1 = q1 - zv.y; lsum += d1 * d1;
        float q2 = zv.z + (ev.z - zv.z); float d2 = q2 - zv.z; lsum += d2 * d2;
        float q3 = zv.w + (ev.w - zv.w); float d3 = q3 - zv.w; lsum += d3 * d3;
        qo[4*j+0] = q0; qo[4*j+1] = q1; qo[4*j+2] = q2; qo[4*j+3] = q3;
    }
    if (h == 0) out[1 + NELEM + mr] = (float)fi;

    // ---- loss: wave reduce -> block partial -> one fp32 atomic into out[0] ----
    // (out[0] zeroed by 4-byte hipMemsetAsync in kernel_launch; fp32 atomic-sum
    //  error over 1024 partials ~1e-6 vs ~2.6e-2 threshold on the loss.)
#pragma unroll
    for (int off = 32; off; off >>= 1) lsum += __shfl_down(lsum, off, 64);
    if (lane == 0) s_wred[wid] = lsum;
    __syncthreads();
    if (tid == 0) {
        float part = (s_wred[0] + s_wred[1]) + (s_wred[2] + s_wred[3]);
        atomicAdd(out, part * (1.25f / 8388608.0f));  // recon + 0.25*commit, /NELEM
    }
}

extern "C" void kernel_launch(void* const* d_in, const int* in_sizes, int n_in,
                              void* d_out, int out_size, void* d_ws, size_t ws_size,
                              hipStream_t stream) {
    const float* z   = (const float*)d_in[0];
    const float* emb = (const float*)d_in[1];
    float* out = (float*)d_out;

    hipMemsetAsync(out, 0, 4, stream);  // zero loss accumulator (capture-safe)
    vq_main<<<NBLK, 256, 0, stream>>>(z, emb, out);
}